// Round 13
// baseline (477.518 us; speedup 1.0000x reference)
//
#include <hip/hip_runtime.h>
#include <math.h>

#define D 128
#define BSH 9                    // bucket = dst >> 9 (512 nodes/bucket)
#define NBMAX 128                // max buckets (N <= 65536)
#define SCAP 64                  // per-bucket LDS staging capacity
#define BPAD 16                  // bucket cursors padded to 64B lines

typedef short bf16x8 __attribute__((ext_vector_type(8)));
typedef float f32x4 __attribute__((ext_vector_type(4)));

__device__ inline unsigned short f2bf(float f) {  // RNE fp32->bf16
  unsigned u = __float_as_uint(f);
  return (unsigned short)((u + 0x7fffu + ((u >> 16) & 1u)) >> 16);
}
__device__ inline float bf2f(unsigned short b) {
  return __uint_as_float(((unsigned)b) << 16);
}
__device__ inline void acc_u4(float* a, uint4 v) {
  a[0] += __uint_as_float(v.x << 16);
  a[1] += __uint_as_float(v.x & 0xffff0000u);
  a[2] += __uint_as_float(v.y << 16);
  a[3] += __uint_as_float(v.y & 0xffff0000u);
  a[4] += __uint_as_float(v.z << 16);
  a[5] += __uint_as_float(v.z & 0xffff0000u);
  a[6] += __uint_as_float(v.w << 16);
  a[7] += __uint_as_float(v.w & 0xffff0000u);
}

// ---------------- bucketed CSR build (records packed: src<<16 | dst) ----------------
__global__ __launch_bounds__(256) void k_bhist(const int* __restrict__ ei,
    int* __restrict__ bcnt, int E, int nb) {
  __shared__ int h[NBMAX];
  for (int i = threadIdx.x; i < NBMAX; i += 256) h[i] = 0;
  __syncthreads();
  for (int e = blockIdx.x * 256 + threadIdx.x; e < E; e += gridDim.x * 256)
    atomicAdd(&h[ei[E + e] >> BSH], 1);
  __syncthreads();
  for (int i = threadIdx.x; i < nb; i += 256)
    if (h[i]) atomicAdd(&bcnt[i * BPAD], h[i]);
}

__global__ __launch_bounds__(128) void k_bktscan(const int* __restrict__ bcnt,
    int* __restrict__ boff, int* __restrict__ bcur, int* __restrict__ row_ptr,
    int nb, int N, int E) {
  int tid = threadIdx.x;
  int v = (tid < nb) ? bcnt[tid * BPAD] : 0;
  int lane = tid & 63, w = tid >> 6;
  int incl = v;
  #pragma unroll
  for (int off = 1; off < 64; off <<= 1) {
    int t = __shfl_up(incl, off, 64);
    if (lane >= off) incl += t;
  }
  __shared__ int ws[2];
  if (lane == 63) ws[w] = incl;
  __syncthreads();
  int excl = incl - v + (w ? ws[0] : 0);
  if (tid < nb) { boff[tid] = excl; bcur[tid * BPAD] = excl; }
  if (tid == nb - 1) boff[nb] = excl + v;
  if (tid == 0) row_ptr[N] = E;
}

__global__ __launch_bounds__(256) void k_bscatter(const int* __restrict__ ei,
    int* __restrict__ bcur, unsigned* __restrict__ pairs, int E, int nb) {
  __shared__ unsigned stage[NBMAX * SCAP];   // 32KB
  __shared__ int scnt[NBMAX];
  __shared__ int sbase[NBMAX];
  __shared__ int pref[NBMAX + 1];
  int tid = threadIdx.x;
  int c0 = blockIdx.x * 2048;
  if (c0 >= E) return;
  int cend = min(c0 + 2048, E);
  for (int i = tid; i < NBMAX; i += 256) scnt[i] = 0;
  __syncthreads();
  for (int e = c0 + tid; e < cend; e += 256) {
    int src = ei[e], dst = ei[E + e];
    unsigned rec = ((unsigned)src << 16) | (unsigned)dst;   // N <= 65536
    int b = dst >> BSH;
    int pos = atomicAdd(&scnt[b], 1);
    if (pos < SCAP) stage[b * SCAP + pos] = rec;
    else {
      int gp = atomicAdd(&bcur[b * BPAD], 1);
      pairs[gp] = rec;
    }
  }
  __syncthreads();
  for (int b = tid; b < nb; b += 256) {
    int cnt = min(scnt[b], SCAP);
    sbase[b] = cnt ? atomicAdd(&bcur[b * BPAD], cnt) : 0;
  }
  __syncthreads();
  if (tid == 0) {
    int r = 0;
    for (int b = 0; b < nb; b++) { pref[b] = r; r += min(scnt[b], SCAP); }
    pref[nb] = r;
  }
  __syncthreads();
  int T = pref[nb];
  for (int j = tid; j < T; j += 256) {
    int lo = 0, hi = nb;
    while (hi - lo > 1) { int mid = (lo + hi) >> 1; if (pref[mid] <= j) lo = mid; else hi = mid; }
    int i = j - pref[lo];
    pairs[sbase[lo] + i] = stage[lo * SCAP + i];
  }
}

__global__ __launch_bounds__(256) void k_bplace(const unsigned* __restrict__ pairs,
    const int* __restrict__ boff, int* __restrict__ row_ptr,
    int* __restrict__ col, int N) {
  int b = blockIdx.x, tid = threadIdx.x;
  int n0 = b << BSH;
  int nn = min(512, N - n0);
  int beg = boff[b], end = boff[b + 1];
  int cnt = end - beg;
  __shared__ int hist[512];
  __shared__ int cursor[512];
  __shared__ int wt[4];
  for (int i = tid; i < 512; i += 256) hist[i] = 0;
  __syncthreads();
  for (int i = tid; i < cnt; i += 256)
    atomicAdd(&hist[pairs[beg + i] & 511], 1);
  __syncthreads();
  int v0 = hist[2 * tid], v1 = hist[2 * tid + 1];
  int s = v0 + v1;
  int lane = tid & 63, w = tid >> 6;
  int incl = s;
  #pragma unroll
  for (int off = 1; off < 64; off <<= 1) {
    int t = __shfl_up(incl, off, 64);
    if (lane >= off) incl += t;
  }
  if (lane == 63) wt[w] = incl;
  __syncthreads();
  if (tid == 0) {
    int r = 0;
    #pragma unroll
    for (int i = 0; i < 4; i++) { int t = wt[i]; wt[i] = r; r += t; }
  }
  __syncthreads();
  int excl = wt[w] + incl - s;
  cursor[2 * tid] = excl;
  cursor[2 * tid + 1] = excl + v0;
  if (2 * tid < nn)     row_ptr[n0 + 2 * tid] = beg + excl;
  if (2 * tid + 1 < nn) row_ptr[n0 + 2 * tid + 1] = beg + excl + v0;
  __syncthreads();
  for (int i = tid; i < cnt; i += 256) {
    unsigned u = pairs[beg + i];
    int p = atomicAdd(&cursor[u & 511], 1);
    col[beg + p] = (int)(u >> 16);
  }
}

// ---------------- weight prep: WT[n][k] = bf16(W[k][n]), 112 blocks ----------------
__global__ __launch_bounds__(256) void k_prep_w(const float* __restrict__ encW,
    const float* __restrict__ W1, const float* __restrict__ W2,
    unsigned short* __restrict__ WT) {
  int b = blockIdx.x >> 4;        // matrix id 0..6
  int chunk = blockIdx.x & 15;    // 1024 elems per chunk
  const float* src;
  if (b == 0) src = encW;
  else if (b & 1) src = W1 + (size_t)((b - 1) / 2) * D * D;
  else src = W2 + (size_t)(b / 2 - 1) * D * D;
  unsigned short* dst = WT + (size_t)b * D * D;
  int e = chunk * 1024 + threadIdx.x;
  #pragma unroll
  for (int it = 0; it < 4; it++, e += 256) {
    int n = e >> 7, k = e & 127;
    dst[n * D + k] = f2bf(src[k * D + n]);
  }
}

// ---------------- fused epilogue scales ----------------
__global__ __launch_bounds__(128) void k_scales(
    const float* __restrict__ enc_b,
    const float* __restrict__ b1, const float* __restrict__ g1,
    const float* __restrict__ be1, const float* __restrict__ rm1, const float* __restrict__ rv1,
    const float* __restrict__ b2, const float* __restrict__ g2,
    const float* __restrict__ be2, const float* __restrict__ rm2, const float* __restrict__ rv2,
    const float* __restrict__ og, const float* __restrict__ ob,
    const float* __restrict__ orm, const float* __restrict__ orv,
    float4* __restrict__ scales) {
  int g = blockIdx.x, c = threadIdx.x;
  float s1 = 1.f, t1 = 0.f, s2 = 1.f, t2 = 0.f;
  if (g == 0) {
    t1 = enc_b[c];
  } else if (g & 1) {
    int l = (g - 1) / 2, i = l * D + c;
    float inv = rsqrtf(rv1[i] + 1e-5f);
    s1 = g1[i] * inv;
    t1 = (b1[i] - rm1[i]) * s1 + be1[i];
  } else {
    int l = g / 2 - 1, i = l * D + c;
    float inv = rsqrtf(rv2[i] + 1e-5f);
    s1 = g2[i] * inv;
    t1 = (b2[i] - rm2[i]) * s1 + be2[i];
    float inv2 = rsqrtf(orv[i] + 1e-5f);
    s2 = og[i] * inv2;
    t2 = ob[i] - orm[i] * s2;
  }
  scales[g * D + c] = make_float4(s1, t1, s2, t2);
}

#define TSTRIDE 136

// shared device helpers for the MFMA kernels
__device__ inline void mfma_gemm(const bf16x8* afr,
    const unsigned short* __restrict__ WT, int l16, int quad, f32x4* acc) {
  #pragma unroll
  for (int t = 0; t < 8; t++) acc[t] = (f32x4){0.f, 0.f, 0.f, 0.f};
  #pragma unroll
  for (int kk = 0; kk < 4; kk++) {
    int koff = kk * 32 + quad * 8;
    #pragma unroll
    for (int t = 0; t < 8; t++) {
      bf16x8 bfr = *(const bf16x8*)(WT + (size_t)(16 * t + l16) * D + koff);
      acc[t] = __builtin_amdgcn_mfma_f32_16x16x32_bf16(afr[kk], bfr, acc[t], 0, 0, 0);
    }
  }
}

__device__ inline void epilogue_to_lds(const f32x4* acc,
    const float4* __restrict__ scales, unsigned short* stile,
    int rl, int l16) {
  #pragma unroll
  for (int t = 0; t < 8; t++) {
    int colc = 16 * t + l16;
    float4 sc = scales[colc];
    #pragma unroll
    for (int reg = 0; reg < 4; reg++) {
      float y = acc[t][reg] * sc.x + sc.y;
      y = fmaxf(y, 0.f);
      y = y * sc.z + sc.w;
      y = fmaxf(y, 0.f);
      stile[(rl + reg) * TSTRIDE + colc] = f2bf(y);
    }
  }
}

// ---------------- encoder MFMA GEMM (fp32 in) ----------------
__global__ __launch_bounds__(256) void k_mfma(const float* __restrict__ in,
    const unsigned short* __restrict__ WT, const float4* __restrict__ scales,
    unsigned short* __restrict__ out, int N) {
  __shared__ unsigned short stile[64 * TSTRIDE];
  int tid = threadIdx.x;
  int wave = tid >> 6, lane = tid & 63;
  int quad = lane >> 4, l16 = lane & 15;
  int rc = min(blockIdx.x * 64 + wave * 16 + l16, N - 1);
  const float* arow = in + (size_t)rc * D;
  bf16x8 afr[4];
  #pragma unroll
  for (int kk = 0; kk < 4; kk++) {
    int koff = kk * 32 + quad * 8;
    float4 lo = *(const float4*)(arow + koff);
    float4 hi = *(const float4*)(arow + koff + 4);
    afr[kk][0] = f2bf(lo.x); afr[kk][1] = f2bf(lo.y);
    afr[kk][2] = f2bf(lo.z); afr[kk][3] = f2bf(lo.w);
    afr[kk][4] = f2bf(hi.x); afr[kk][5] = f2bf(hi.y);
    afr[kk][6] = f2bf(hi.z); afr[kk][7] = f2bf(hi.w);
  }
  f32x4 acc[8];
  mfma_gemm(afr, WT, l16, quad, acc);
  epilogue_to_lds(acc, scales, stile, wave * 16 + quad * 4, l16);
  __syncthreads();
  #pragma unroll
  for (int u = tid; u < 1024; u += 256) {
    int r = u >> 4, cs = (u & 15) * 8;
    int row = blockIdx.x * 64 + r;
    if (row < N)
      *(uint4*)(out + (size_t)row * D + cs) = *(const uint4*)&stile[r * TSTRIDE + cs];
  }
}

// ---------------- fused GIN layer: aggregate + GEMM pair (R10 phase-A form) ----------------
__global__ __launch_bounds__(256) void k_layer(const unsigned short* __restrict__ h,
    const int* __restrict__ row_ptr, const int* __restrict__ col,
    const float* __restrict__ eps, int layer,
    const unsigned short* __restrict__ WT1, const unsigned short* __restrict__ WT2,
    const float4* __restrict__ sc1, const float4* __restrict__ sc2,
    unsigned short* __restrict__ out, int N) {
  __shared__ unsigned short stile[64 * TSTRIDE];
  int tid = threadIdx.x;
  float ep = 1.0f + eps[layer];
  int rloc = tid >> 4;           // 16 lanes per node
  int c = (tid & 15) << 3;       // 8 bf16 cols per lane (16B loads)

  // phase A: aggregate 64 nodes (4 sub-batches of 16) -> stile (bf16 m-tile)
  for (int sub = 0; sub < 4; sub++) {
    int nl = sub * 16 + rloc;
    int node = blockIdx.x * 64 + nl;
    float acc[8];
    #pragma unroll
    for (int j = 0; j < 8; j++) acc[j] = 0.f;
    if (node < N) {
      int beg = row_ptr[node], end = row_ptr[node + 1];
      int i = beg;
      for (; i + 3 < end; i += 4) {
        int s0 = col[i], s1 = col[i + 1], s2 = col[i + 2], s3 = col[i + 3];
        uint4 v0 = *(const uint4*)(h + (size_t)s0 * D + c);
        uint4 v1 = *(const uint4*)(h + (size_t)s1 * D + c);
        uint4 v2 = *(const uint4*)(h + (size_t)s2 * D + c);
        uint4 v3 = *(const uint4*)(h + (size_t)s3 * D + c);
        acc_u4(acc, v0); acc_u4(acc, v1); acc_u4(acc, v2); acc_u4(acc, v3);
      }
      for (; i < end; i++)
        acc_u4(acc, *(const uint4*)(h + (size_t)col[i] * D + c));
      uint4 hv = *(const uint4*)(h + (size_t)node * D + c);
      float sv[8] = {0.f, 0.f, 0.f, 0.f, 0.f, 0.f, 0.f, 0.f};
      acc_u4(sv, hv);
      #pragma unroll
      for (int j = 0; j < 8; j++) acc[j] = fmaf(ep, sv[j], acc[j]);
    }
    uint4 o;
    o.x = (unsigned)f2bf(acc[0]) | ((unsigned)f2bf(acc[1]) << 16);
    o.y = (unsigned)f2bf(acc[2]) | ((unsigned)f2bf(acc[3]) << 16);
    o.z = (unsigned)f2bf(acc[4]) | ((unsigned)f2bf(acc[5]) << 16);
    o.w = (unsigned)f2bf(acc[6]) | ((unsigned)f2bf(acc[7]) << 16);
    *(uint4*)&stile[nl * TSTRIDE + c] = o;
  }
  __syncthreads();

  // phase B: GEMM pair, A-fragments from stile
  int wave = tid >> 6, lane = tid & 63;
  int quad = lane >> 4, l16 = lane & 15;
  int rl = wave * 16 + quad * 4;
  bf16x8 afr[4];
  const unsigned short* lrow = &stile[(wave * 16 + l16) * TSTRIDE];
  #pragma unroll
  for (int kk = 0; kk < 4; kk++)
    afr[kk] = *(const bf16x8*)(lrow + kk * 32 + quad * 8);
  __syncthreads();   // all reads done before epilogue overwrites

  f32x4 acc[8];
  mfma_gemm(afr, WT1, l16, quad, acc);
  epilogue_to_lds(acc, sc1, stile, rl, l16);
  __syncthreads();

  #pragma unroll
  for (int kk = 0; kk < 4; kk++)
    afr[kk] = *(const bf16x8*)(lrow + kk * 32 + quad * 8);
  __syncthreads();

  mfma_gemm(afr, WT2, l16, quad, acc);
  epilogue_to_lds(acc, sc2, stile, rl, l16);
  __syncthreads();

  #pragma unroll
  for (int u = tid; u < 1024; u += 256) {
    int r = u >> 4, cs = (u & 15) * 8;
    int row = blockIdx.x * 64 + r;
    if (row < N)
      *(uint4*)(out + (size_t)row * D + cs) = *(const uint4*)&stile[r * TSTRIDE + cs];
  }
}

// ---------------- attention MLP + fused pool (batch sorted) ----------------
// LDS layout (floats): sH [0,8192) | phase1: sW1 [8192,16384)
// after phase1: a1B [8192,12544) (stride 68), sW2 [12544,14592),
// a2B [14592,16896) (stride 36), sscore [16896,16960), sbat [16960,17024)
__global__ __launch_bounds__(256) void k_attention(const unsigned short* __restrict__ h,
    const float* __restrict__ aW1, const float* __restrict__ ab1,
    const float* __restrict__ aW2, const float* __restrict__ ab2,
    const float* __restrict__ aW3, const float* __restrict__ ab3,
    const float* __restrict__ temp, const int* __restrict__ batch,
    float* __restrict__ scores, float* __restrict__ ge, int n) {
  __shared__ float smem[17024];              // 68KB
  float* sH  = smem;                         // [64][128]
  float* sW1 = smem + 8192;                  // [128][64]
  int tid = threadIdx.x;
  int node0 = blockIdx.x * 64;

  for (int i = tid; i < 1024; i += 256) {
    int r = i >> 4, c8 = (i & 15) << 3;
    int nd = min(node0 + r, n - 1);
    uint4 u = *(const uint4*)(h + (size_t)nd * D + c8);
    float* dst = &sH[r * 128 + c8];
    dst[0] = __uint_as_float(u.x << 16); dst[1] = __uint_as_float(u.x & 0xffff0000u);
    dst[2] = __uint_as_float(u.y << 16); dst[3] = __uint_as_float(u.y & 0xffff0000u);
    dst[4] = __uint_as_float(u.z << 16); dst[5] = __uint_as_float(u.z & 0xffff0000u);
    dst[6] = __uint_as_float(u.w << 16); dst[7] = __uint_as_float(u.w & 0xffff0000u);
  }
  for (int i4 = tid; i4 < 2048; i4 += 256)
    *(float4*)&sW1[i4 * 4] = *(const float4*)(aW1 + i4 * 4);
  if (tid < 64) ((int*)(smem + 16960))[tid] = batch[min(node0 + tid, n - 1)];
  __syncthreads();

  int tx = tid & 31, ty = tid >> 5;
  int c0 = tx * 2, r0 = ty * 8;
  float acc[8][2];
  #pragma unroll
  for (int i = 0; i < 8; i++) { acc[i][0] = 0.f; acc[i][1] = 0.f; }
  #pragma unroll 4
  for (int kk = 0; kk < 128; kk += 4) {
    float2 b0 = *(float2*)&sW1[(kk + 0) * 64 + c0];
    float2 b1 = *(float2*)&sW1[(kk + 1) * 64 + c0];
    float2 b2 = *(float2*)&sW1[(kk + 2) * 64 + c0];
    float2 b3 = *(float2*)&sW1[(kk + 3) * 64 + c0];
    #pragma unroll
    for (int i = 0; i < 8; i++) {
      float4 a = *(float4*)&sH[(r0 + i) * 128 + kk];
      acc[i][0] += a.x * b0.x + a.y * b1.x + a.z * b2.x + a.w * b3.x;
      acc[i][1] += a.x * b0.y + a.y * b1.y + a.z * b2.y + a.w * b3.y;
    }
  }
  float bb0 = ab1[c0], bb1 = ab1[c0 + 1];
  __syncthreads();

  float* a1B = smem + 8192;                   // [64][68]
  float* sW2 = smem + 12544;                  // [64][32]
  float* a2B = smem + 14592;                  // [64][36]
  float* sscore = smem + 16896;               // [64]
  const int* sbat = (const int*)(smem + 16960);
  #pragma unroll
  for (int i = 0; i < 8; i++) {
    float v0 = acc[i][0] + bb0; v0 = fmaxf(v0, 0.2f * v0);
    float v1 = acc[i][1] + bb1; v1 = fmaxf(v1, 0.2f * v1);
    *(float2*)&a1B[(r0 + i) * 68 + c0] = make_float2(v0, v1);
  }
  for (int i4 = tid; i4 < 512; i4 += 256)
    *(float4*)&sW2[i4 * 4] = *(const float4*)(aW2 + i4 * 4);
  __syncthreads();

  int tx2 = tid & 7, ty2 = tid >> 3;
  int cc0 = tx2 * 4, rr0 = ty2 * 2;
  float acc2[2][4];
  #pragma unroll
  for (int i = 0; i < 2; i++)
    #pragma unroll
    for (int j = 0; j < 4; j++) acc2[i][j] = 0.f;
  #pragma unroll 4
  for (int k = 0; k < 64; k += 4) {
    float4 b0 = *(float4*)&sW2[(k + 0) * 32 + cc0];
    float4 b1 = *(float4*)&sW2[(k + 1) * 32 + cc0];
    float4 b2 = *(float4*)&sW2[(k + 2) * 32 + cc0];
    float4 b3 = *(float4*)&sW2[(k + 3) * 32 + cc0];
    #pragma unroll
    for (int i = 0; i < 2; i++) {
      float4 a = *(float4*)&a1B[(rr0 + i) * 68 + k];
      acc2[i][0] += a.x * b0.x + a.y * b1.x + a.z * b2.x + a.w * b3.x;
      acc2[i][1] += a.x * b0.y + a.y * b1.y + a.z * b2.y + a.w * b3.y;
      acc2[i][2] += a.x * b0.z + a.y * b1.z + a.z * b2.z + a.w * b3.z;
      acc2[i][3] += a.x * b0.w + a.y * b1.w + a.z * b2.w + a.w * b3.w;
    }
  }
  float4 bias2 = *(const float4*)(ab2 + cc0);
  #pragma unroll
  for (int i = 0; i < 2; i++) {
    float4 o;
    o.x = acc2[i][0] + bias2.x; o.x = fmaxf(o.x, 0.2f * o.x);
    o.y = acc2[i][1] + bias2.y; o.y = fmaxf(o.y, 0.2f * o.y);
    o.z = acc2[i][2] + bias2.z; o.z = fmaxf(o.z, 0.2f * o.z);
    o.w = acc2[i][3] + bias2.w; o.w = fmaxf(o.w, 0.2f * o.w);
    *(float4*)&a2B[(rr0 + i) * 36 + cc0] = o;
  }
  __syncthreads();

  if (tid < 64) {
    float s = ab3[0];
    #pragma unroll 8
    for (int k = 0; k < 32; k++) s = fmaf(a2B[tid * 36 + k], aW3[k], s);
    s = fminf(fmaxf(s, -10.f), 10.f);
    float sg = 1.0f / (1.0f + __expf(-s * temp[0]));
    int node = node0 + tid;
    sscore[tid] = (node < n) ? sg : 0.f;
    if (node < n) scores[node] = sg;
  }
  __syncthreads();

  // fused pool: segmented reduce over this block's 64 rows (batch sorted)
  if (tid < 128) {
    int f = tid;
    float pacc = 0.f;
    int cur = sbat[0];
    int lim = min(64, n - node0);
    for (int i = 0; i < lim; i++) {
      int b = sbat[i];
      if (b != cur) {
        atomicAdd(&ge[(size_t)cur * D + f], pacc);
        pacc = 0.f;
        cur = b;
      }
      pacc = fmaf(sH[i * 128 + f], sscore[i], pacc);
    }
    if (lim > 0) atomicAdd(&ge[(size_t)cur * D + f], pacc);
  }
}

// ---------------- classifier: block per graph ----------------
__global__ __launch_bounds__(128) void k_classifier(const float* __restrict__ ge,
    const float* __restrict__ cW1, const float* __restrict__ cb1,
    const float* __restrict__ cW2, const float* __restrict__ cb2,
    float* __restrict__ logits, int B) {
  __shared__ float sg[D];
  __shared__ float st[D];
  int g = blockIdx.x;
  int tid = threadIdx.x;
  sg[tid] = ge[(size_t)g * D + tid];
  __syncthreads();
  float a = cb1[tid];
  #pragma unroll 8
  for (int k = 0; k < D; k++) a = fmaf(sg[k], cW1[k * D + tid], a);
  st[tid] = fmaxf(a, 0.f);
  __syncthreads();
  if (tid < 3) {
    float a2 = cb2[tid];
    for (int k = 0; k < D; k++) a2 = fmaf(st[k], cW2[k * 3 + tid], a2);
    logits[(size_t)g * 3 + tid] = a2;
  }
}

extern "C" void kernel_launch(void* const* d_in, const int* in_sizes, int n_in,
                              void* d_out, int out_size, void* d_ws, size_t ws_size,
                              hipStream_t stream) {
  const float* x     = (const float*)d_in[0];
  const int*   ei    = (const int*)d_in[1];
  const int*   batch = (const int*)d_in[2];
  const float* enc_W = (const float*)d_in[3];
  const float* enc_b = (const float*)d_in[4];
  const float* W1    = (const float*)d_in[5];
  const float* b1    = (const float*)d_in[6];
  const float* g1    = (const float*)d_in[7];
  const float* beta1 = (const float*)d_in[8];
  const float* rm1   = (const float*)d_in[9];
  const float* rv1   = (const float*)d_in[10];
  const float* W2    = (const float*)d_in[11];
  const float* b2    = (const float*)d_in[12];
  const float* g2    = (const float*)d_in[13];
  const float* beta2 = (const float*)d_in[14];
  const float* rm2   = (const float*)d_in[15];
  const float* rv2   = (const float*)d_in[16];
  const float* eps   = (const float*)d_in[17];
  const float* og    = (const float*)d_in[18];
  const float* ob    = (const float*)d_in[19];
  const float* orm   = (const float*)d_in[20];
  const float* orv   = (const float*)d_in[21];
  const float* aW1   = (const float*)d_in[22];
  const float* ab1   = (const float*)d_in[23];
  const float* aW2   = (const float*)d_in[24];
  const float* ab2   = (const float*)d_in[25];
  const float* aW3   = (const float*)d_in[26];
  const float* ab3   = (const float*)d_in[27];
  const float* temp  = (const float*)d_in[28];
  const float* cW1   = (const float*)d_in[29];
  const float* cb1   = (const float*)d_in[30];
  const float* cW2   = (const float*)d_in[31];
  const float* cb2   = (const float*)d_in[32];

  int N = in_sizes[0] / D;
  int E = in_sizes[1] / 2;
  int B = (out_size - N) / (3 + D);
  int nb = (N + 511) >> BSH;     // buckets of 512 nodes (<=128 for N<=65536)

  // workspace layout (hbufA/hbufB ping-pong across layers)
  unsigned short* hbufA = (unsigned short*)d_ws;
  unsigned short* hbufB = hbufA + (size_t)N * D;
  int* row_ptr = (int*)(hbufB + (size_t)N * D);
  int* colidx  = row_ptr + N + 1;
  int* bcnt    = colidx + E;            // nb*BPAD
  int* boff    = bcnt + nb * BPAD;      // nb+1
  int* bcur    = boff + nb + 1;         // nb*BPAD
  uintptr_t p = (uintptr_t)(bcur + nb * BPAD);
  p = (p + 15) & ~(uintptr_t)15;
  unsigned* pairs = (unsigned*)p;       // E packed records
  unsigned short* WT = (unsigned short*)(pairs + E);   // 7*128*128 bf16
  float4* sc_all = (float4*)(WT + 7 * D * D);          // 7*128 float4

  float* logits = (float*)d_out;
  float* ge     = logits + (size_t)B * 3;
  float* scores = ge + (size_t)B * D;

  k_prep_w<<<112, 256, 0, stream>>>(enc_W, W1, W2, WT);
  k_scales<<<7, 128, 0, stream>>>(enc_b, b1, g1, beta1, rm1, rv1,
                                  b2, g2, beta2, rm2, rv2, og, ob, orm, orv, sc_all);

  // bucketed CSR build (packed 4B records, LDS-staged scatter)
  hipMemsetAsync(bcnt, 0, (size_t)nb * BPAD * sizeof(int), stream);
  k_bhist<<<256, 256, 0, stream>>>(ei, bcnt, E, nb);
  k_bktscan<<<1, 128, 0, stream>>>(bcnt, boff, bcur, row_ptr, nb, N, E);
  k_bscatter<<<(E + 2047) / 2048, 256, 0, stream>>>(ei, bcur, pairs, E, nb);
  k_bplace<<<nb, 256, 0, stream>>>(pairs, boff, row_ptr, colidx, N);

  int gblocks = (N + 63) / 64;
  // encoder: h = relu(x@enc_W + enc_b)
  k_mfma<<<gblocks, 256, 0, stream>>>(x, WT, sc_all, hbufA, N);

  unsigned short* cur = hbufA;
  unsigned short* nxt = hbufB;
  for (int l = 0; l < 3; l++) {
    k_layer<<<gblocks, 256, 0, stream>>>(cur, row_ptr, colidx, eps, l,
        WT + (size_t)(1 + 2 * l) * D * D, WT + (size_t)(2 + 2 * l) * D * D,
        sc_all + (1 + 2 * l) * D, sc_all + (2 + 2 * l) * D, nxt, N);
    unsigned short* t = cur; cur = nxt; nxt = t;
  }

  hipMemsetAsync(ge, 0, (size_t)B * D * sizeof(float), stream);
  k_attention<<<gblocks, 256, 0, stream>>>(cur, aW1, ab1, aW2, ab2, aW3, ab3,
                                           temp, batch, scores, ge, N);
  k_classifier<<<B, 128, 0, stream>>>(ge, cW1, cb1, cW2, cb2, logits, B);
}

// Round 14
// 440.416 us; speedup vs baseline: 1.0842x; 1.0842x over previous
//
#include <hip/hip_runtime.h>
#include <math.h>

#define D 128
#define BSH 9                    // bucket = dst >> 9 (512 nodes/bucket)
#define NBMAX 128                // max buckets (N <= 65536)
#define SCAP 64                  // per-bucket LDS staging capacity
#define BPAD 16                  // bucket cursors padded to 64B lines

typedef short bf16x8 __attribute__((ext_vector_type(8)));
typedef float f32x4 __attribute__((ext_vector_type(4)));

__device__ inline unsigned short f2bf(float f) {  // RNE fp32->bf16
  unsigned u = __float_as_uint(f);
  return (unsigned short)((u + 0x7fffu + ((u >> 16) & 1u)) >> 16);
}
__device__ inline float bf2f(unsigned short b) {
  return __uint_as_float(((unsigned)b) << 16);
}
__device__ inline void acc_u4(float* a, uint4 v) {
  a[0] += __uint_as_float(v.x << 16);
  a[1] += __uint_as_float(v.x & 0xffff0000u);
  a[2] += __uint_as_float(v.y << 16);
  a[3] += __uint_as_float(v.y & 0xffff0000u);
  a[4] += __uint_as_float(v.z << 16);
  a[5] += __uint_as_float(v.z & 0xffff0000u);
  a[6] += __uint_as_float(v.w << 16);
  a[7] += __uint_as_float(v.w & 0xffff0000u);
}

// ---------------- bucketed CSR build (records packed: src<<16 | dst) ----------------
__global__ __launch_bounds__(256) void k_bhist(const int* __restrict__ ei,
    int* __restrict__ bcnt, int E, int nb) {
  __shared__ int h[NBMAX];
  for (int i = threadIdx.x; i < NBMAX; i += 256) h[i] = 0;
  __syncthreads();
  for (int e = blockIdx.x * 256 + threadIdx.x; e < E; e += gridDim.x * 256)
    atomicAdd(&h[ei[E + e] >> BSH], 1);
  __syncthreads();
  for (int i = threadIdx.x; i < nb; i += 256)
    if (h[i]) atomicAdd(&bcnt[i * BPAD], h[i]);
}

__global__ __launch_bounds__(128) void k_bktscan(const int* __restrict__ bcnt,
    int* __restrict__ boff, int* __restrict__ bcur, int* __restrict__ row_ptr,
    int nb, int N, int E) {
  int tid = threadIdx.x;
  int v = (tid < nb) ? bcnt[tid * BPAD] : 0;
  int lane = tid & 63, w = tid >> 6;
  int incl = v;
  #pragma unroll
  for (int off = 1; off < 64; off <<= 1) {
    int t = __shfl_up(incl, off, 64);
    if (lane >= off) incl += t;
  }
  __shared__ int ws[2];
  if (lane == 63) ws[w] = incl;
  __syncthreads();
  int excl = incl - v + (w ? ws[0] : 0);
  if (tid < nb) { boff[tid] = excl; bcur[tid * BPAD] = excl; }
  if (tid == nb - 1) boff[nb] = excl + v;
  if (tid == 0) row_ptr[N] = E;
}

__global__ __launch_bounds__(256) void k_bscatter(const int* __restrict__ ei,
    int* __restrict__ bcur, unsigned* __restrict__ pairs, int E, int nb) {
  __shared__ unsigned stage[NBMAX * SCAP];   // 32KB
  __shared__ int scnt[NBMAX];
  __shared__ int sbase[NBMAX];
  __shared__ int pref[NBMAX + 1];
  int tid = threadIdx.x;
  int c0 = blockIdx.x * 2048;
  if (c0 >= E) return;
  int cend = min(c0 + 2048, E);
  for (int i = tid; i < NBMAX; i += 256) scnt[i] = 0;
  __syncthreads();
  for (int e = c0 + tid; e < cend; e += 256) {
    int src = ei[e], dst = ei[E + e];
    unsigned rec = ((unsigned)src << 16) | (unsigned)dst;   // N <= 65536
    int b = dst >> BSH;
    int pos = atomicAdd(&scnt[b], 1);
    if (pos < SCAP) stage[b * SCAP + pos] = rec;
    else {
      int gp = atomicAdd(&bcur[b * BPAD], 1);
      pairs[gp] = rec;
    }
  }
  __syncthreads();
  for (int b = tid; b < nb; b += 256) {
    int cnt = min(scnt[b], SCAP);
    sbase[b] = cnt ? atomicAdd(&bcur[b * BPAD], cnt) : 0;
  }
  __syncthreads();
  if (tid == 0) {
    int r = 0;
    for (int b = 0; b < nb; b++) { pref[b] = r; r += min(scnt[b], SCAP); }
    pref[nb] = r;
  }
  __syncthreads();
  int T = pref[nb];
  for (int j = tid; j < T; j += 256) {
    int lo = 0, hi = nb;
    while (hi - lo > 1) { int mid = (lo + hi) >> 1; if (pref[mid] <= j) lo = mid; else hi = mid; }
    int i = j - pref[lo];
    pairs[sbase[lo] + i] = stage[lo * SCAP + i];
  }
}

__global__ __launch_bounds__(256) void k_bplace(const unsigned* __restrict__ pairs,
    const int* __restrict__ boff, int* __restrict__ row_ptr,
    int* __restrict__ col, int N) {
  int b = blockIdx.x, tid = threadIdx.x;
  int n0 = b << BSH;
  int nn = min(512, N - n0);
  int beg = boff[b], end = boff[b + 1];
  int cnt = end - beg;
  __shared__ int hist[512];
  __shared__ int cursor[512];
  __shared__ int wt[4];
  for (int i = tid; i < 512; i += 256) hist[i] = 0;
  __syncthreads();
  for (int i = tid; i < cnt; i += 256)
    atomicAdd(&hist[pairs[beg + i] & 511], 1);
  __syncthreads();
  int v0 = hist[2 * tid], v1 = hist[2 * tid + 1];
  int s = v0 + v1;
  int lane = tid & 63, w = tid >> 6;
  int incl = s;
  #pragma unroll
  for (int off = 1; off < 64; off <<= 1) {
    int t = __shfl_up(incl, off, 64);
    if (lane >= off) incl += t;
  }
  if (lane == 63) wt[w] = incl;
  __syncthreads();
  if (tid == 0) {
    int r = 0;
    #pragma unroll
    for (int i = 0; i < 4; i++) { int t = wt[i]; wt[i] = r; r += t; }
  }
  __syncthreads();
  int excl = wt[w] + incl - s;
  cursor[2 * tid] = excl;
  cursor[2 * tid + 1] = excl + v0;
  if (2 * tid < nn)     row_ptr[n0 + 2 * tid] = beg + excl;
  if (2 * tid + 1 < nn) row_ptr[n0 + 2 * tid + 1] = beg + excl + v0;
  __syncthreads();
  for (int i = tid; i < cnt; i += 256) {
    unsigned u = pairs[beg + i];
    int p = atomicAdd(&cursor[u & 511], 1);
    col[beg + p] = (int)(u >> 16);
  }
}

// ---------------- weight prep: WT[n][k] = bf16(W[k][n]), 112 blocks ----------------
__global__ __launch_bounds__(256) void k_prep_w(const float* __restrict__ encW,
    const float* __restrict__ W1, const float* __restrict__ W2,
    unsigned short* __restrict__ WT) {
  int b = blockIdx.x >> 4;        // matrix id 0..6
  int chunk = blockIdx.x & 15;    // 1024 elems per chunk
  const float* src;
  if (b == 0) src = encW;
  else if (b & 1) src = W1 + (size_t)((b - 1) / 2) * D * D;
  else src = W2 + (size_t)(b / 2 - 1) * D * D;
  unsigned short* dst = WT + (size_t)b * D * D;
  int e = chunk * 1024 + threadIdx.x;
  #pragma unroll
  for (int it = 0; it < 4; it++, e += 256) {
    int n = e >> 7, k = e & 127;
    dst[n * D + k] = f2bf(src[k * D + n]);
  }
}

// ---------------- fused epilogue scales ----------------
__global__ __launch_bounds__(128) void k_scales(
    const float* __restrict__ enc_b,
    const float* __restrict__ b1, const float* __restrict__ g1,
    const float* __restrict__ be1, const float* __restrict__ rm1, const float* __restrict__ rv1,
    const float* __restrict__ b2, const float* __restrict__ g2,
    const float* __restrict__ be2, const float* __restrict__ rm2, const float* __restrict__ rv2,
    const float* __restrict__ og, const float* __restrict__ ob,
    const float* __restrict__ orm, const float* __restrict__ orv,
    float4* __restrict__ scales) {
  int g = blockIdx.x, c = threadIdx.x;
  float s1 = 1.f, t1 = 0.f, s2 = 1.f, t2 = 0.f;
  if (g == 0) {
    t1 = enc_b[c];
  } else if (g & 1) {
    int l = (g - 1) / 2, i = l * D + c;
    float inv = rsqrtf(rv1[i] + 1e-5f);
    s1 = g1[i] * inv;
    t1 = (b1[i] - rm1[i]) * s1 + be1[i];
  } else {
    int l = g / 2 - 1, i = l * D + c;
    float inv = rsqrtf(rv2[i] + 1e-5f);
    s1 = g2[i] * inv;
    t1 = (b2[i] - rm2[i]) * s1 + be2[i];
    float inv2 = rsqrtf(orv[i] + 1e-5f);
    s2 = og[i] * inv2;
    t2 = ob[i] - orm[i] * s2;
  }
  scales[g * D + c] = make_float4(s1, t1, s2, t2);
}

#define TSTRIDE 136

// shared device helpers for the MFMA kernels
__device__ inline void mfma_gemm(const bf16x8* afr,
    const unsigned short* __restrict__ WT, int l16, int quad, f32x4* acc) {
  #pragma unroll
  for (int t = 0; t < 8; t++) acc[t] = (f32x4){0.f, 0.f, 0.f, 0.f};
  #pragma unroll
  for (int kk = 0; kk < 4; kk++) {
    int koff = kk * 32 + quad * 8;
    #pragma unroll
    for (int t = 0; t < 8; t++) {
      bf16x8 bfr = *(const bf16x8*)(WT + (size_t)(16 * t + l16) * D + koff);
      acc[t] = __builtin_amdgcn_mfma_f32_16x16x32_bf16(afr[kk], bfr, acc[t], 0, 0, 0);
    }
  }
}

__device__ inline void epilogue_to_lds(const f32x4* acc,
    const float4* __restrict__ scales, unsigned short* stile,
    int rl, int l16) {
  #pragma unroll
  for (int t = 0; t < 8; t++) {
    int colc = 16 * t + l16;
    float4 sc = scales[colc];
    #pragma unroll
    for (int reg = 0; reg < 4; reg++) {
      float y = acc[t][reg] * sc.x + sc.y;
      y = fmaxf(y, 0.f);
      y = y * sc.z + sc.w;
      y = fmaxf(y, 0.f);
      stile[(rl + reg) * TSTRIDE + colc] = f2bf(y);
    }
  }
}

// ---------------- encoder MFMA GEMM (fp32 in) ----------------
__global__ __launch_bounds__(256) void k_mfma(const float* __restrict__ in,
    const unsigned short* __restrict__ WT, const float4* __restrict__ scales,
    unsigned short* __restrict__ out, int N) {
  __shared__ unsigned short stile[64 * TSTRIDE];
  int tid = threadIdx.x;
  int wave = tid >> 6, lane = tid & 63;
  int quad = lane >> 4, l16 = lane & 15;
  int rc = min(blockIdx.x * 64 + wave * 16 + l16, N - 1);
  const float* arow = in + (size_t)rc * D;
  bf16x8 afr[4];
  #pragma unroll
  for (int kk = 0; kk < 4; kk++) {
    int koff = kk * 32 + quad * 8;
    float4 lo = *(const float4*)(arow + koff);
    float4 hi = *(const float4*)(arow + koff + 4);
    afr[kk][0] = f2bf(lo.x); afr[kk][1] = f2bf(lo.y);
    afr[kk][2] = f2bf(lo.z); afr[kk][3] = f2bf(lo.w);
    afr[kk][4] = f2bf(hi.x); afr[kk][5] = f2bf(hi.y);
    afr[kk][6] = f2bf(hi.z); afr[kk][7] = f2bf(hi.w);
  }
  f32x4 acc[8];
  mfma_gemm(afr, WT, l16, quad, acc);
  epilogue_to_lds(acc, scales, stile, wave * 16 + quad * 4, l16);
  __syncthreads();
  #pragma unroll
  for (int u = tid; u < 1024; u += 256) {
    int r = u >> 4, cs = (u & 15) * 8;
    int row = blockIdx.x * 64 + r;
    if (row < N)
      *(uint4*)(out + (size_t)row * D + cs) = *(const uint4*)&stile[r * TSTRIDE + cs];
  }
}

// ---------------- fused GIN layer: 128 threads / 32-row tile (grid 2x for occupancy) ----------------
__global__ __launch_bounds__(128) void k_layer(const unsigned short* __restrict__ h,
    const int* __restrict__ row_ptr, const int* __restrict__ col,
    const float* __restrict__ eps, int layer,
    const unsigned short* __restrict__ WT1, const unsigned short* __restrict__ WT2,
    const float4* __restrict__ sc1, const float4* __restrict__ sc2,
    unsigned short* __restrict__ out, int N) {
  __shared__ unsigned short stile[32 * TSTRIDE];   // 8.7KB
  int tid = threadIdx.x;
  float ep = 1.0f + eps[layer];
  int rloc = tid >> 4;           // 0..7: 16 lanes per node
  int c = (tid & 15) << 3;       // 8 bf16 cols per lane (16B loads)

  // phase A: aggregate 32 nodes (4 sub-batches of 8) -> stile (bf16 m-tile)
  for (int sub = 0; sub < 4; sub++) {
    int nl = sub * 8 + rloc;
    int node = blockIdx.x * 32 + nl;
    float acc[8];
    #pragma unroll
    for (int j = 0; j < 8; j++) acc[j] = 0.f;
    if (node < N) {
      int beg = row_ptr[node], end = row_ptr[node + 1];
      int i = beg;
      for (; i + 3 < end; i += 4) {
        int s0 = col[i], s1 = col[i + 1], s2 = col[i + 2], s3 = col[i + 3];
        uint4 v0 = *(const uint4*)(h + (size_t)s0 * D + c);
        uint4 v1 = *(const uint4*)(h + (size_t)s1 * D + c);
        uint4 v2 = *(const uint4*)(h + (size_t)s2 * D + c);
        uint4 v3 = *(const uint4*)(h + (size_t)s3 * D + c);
        acc_u4(acc, v0); acc_u4(acc, v1); acc_u4(acc, v2); acc_u4(acc, v3);
      }
      for (; i < end; i++)
        acc_u4(acc, *(const uint4*)(h + (size_t)col[i] * D + c));
      uint4 hv = *(const uint4*)(h + (size_t)node * D + c);
      float sv[8] = {0.f, 0.f, 0.f, 0.f, 0.f, 0.f, 0.f, 0.f};
      acc_u4(sv, hv);
      #pragma unroll
      for (int j = 0; j < 8; j++) acc[j] = fmaf(ep, sv[j], acc[j]);
    }
    uint4 o;
    o.x = (unsigned)f2bf(acc[0]) | ((unsigned)f2bf(acc[1]) << 16);
    o.y = (unsigned)f2bf(acc[2]) | ((unsigned)f2bf(acc[3]) << 16);
    o.z = (unsigned)f2bf(acc[4]) | ((unsigned)f2bf(acc[5]) << 16);
    o.w = (unsigned)f2bf(acc[6]) | ((unsigned)f2bf(acc[7]) << 16);
    *(uint4*)&stile[nl * TSTRIDE + c] = o;
  }
  __syncthreads();

  // phase B: GEMM pair (2 waves x 16 rows), A-fragments from stile
  int wave = tid >> 6, lane = tid & 63;
  int quad = lane >> 4, l16 = lane & 15;
  int rl = wave * 16 + quad * 4;
  bf16x8 afr[4];
  const unsigned short* lrow = &stile[(wave * 16 + l16) * TSTRIDE];
  #pragma unroll
  for (int kk = 0; kk < 4; kk++)
    afr[kk] = *(const bf16x8*)(lrow + kk * 32 + quad * 8);
  __syncthreads();   // all reads done before epilogue overwrites

  f32x4 acc[8];
  mfma_gemm(afr, WT1, l16, quad, acc);
  epilogue_to_lds(acc, sc1, stile, rl, l16);
  __syncthreads();

  #pragma unroll
  for (int kk = 0; kk < 4; kk++)
    afr[kk] = *(const bf16x8*)(lrow + kk * 32 + quad * 8);
  __syncthreads();

  mfma_gemm(afr, WT2, l16, quad, acc);
  epilogue_to_lds(acc, sc2, stile, rl, l16);
  __syncthreads();

  // writeout: 32 rows x 128 shorts = 512 uint4s; 4 per thread
  #pragma unroll
  for (int u = tid; u < 512; u += 128) {
    int r = u >> 4, cs = (u & 15) * 8;
    int row = blockIdx.x * 32 + r;
    if (row < N)
      *(uint4*)(out + (size_t)row * D + cs) = *(const uint4*)&stile[r * TSTRIDE + cs];
  }
}

// ---------------- attention MLP: fused LDS-tiled 3-stage GEMM (h bf16) ----------------
__global__ __launch_bounds__(256) void k_attention(const unsigned short* __restrict__ h,
    const float* __restrict__ aW1, const float* __restrict__ ab1,
    const float* __restrict__ aW2, const float* __restrict__ ab2,
    const float* __restrict__ aW3, const float* __restrict__ ab3,
    const float* __restrict__ temp, float* __restrict__ scores, int n) {
  __shared__ float smem[16384];              // 64KB
  float* sH  = smem;                         // [64][128]
  float* sW1 = smem + 8192;                  // [128][64]
  int tid = threadIdx.x;
  int node0 = blockIdx.x * 64;

  for (int i = tid; i < 1024; i += 256) {
    int r = i >> 4, c8 = (i & 15) << 3;
    int nd = min(node0 + r, n - 1);
    uint4 u = *(const uint4*)(h + (size_t)nd * D + c8);
    float* dst = &sH[r * 128 + c8];
    dst[0] = __uint_as_float(u.x << 16); dst[1] = __uint_as_float(u.x & 0xffff0000u);
    dst[2] = __uint_as_float(u.y << 16); dst[3] = __uint_as_float(u.y & 0xffff0000u);
    dst[4] = __uint_as_float(u.z << 16); dst[5] = __uint_as_float(u.z & 0xffff0000u);
    dst[6] = __uint_as_float(u.w << 16); dst[7] = __uint_as_float(u.w & 0xffff0000u);
  }
  for (int i4 = tid; i4 < 2048; i4 += 256)
    *(float4*)&sW1[i4 * 4] = *(const float4*)(aW1 + i4 * 4);
  __syncthreads();

  int tx = tid & 31, ty = tid >> 5;
  int c0 = tx * 2, r0 = ty * 8;
  float acc[8][2];
  #pragma unroll
  for (int i = 0; i < 8; i++) { acc[i][0] = 0.f; acc[i][1] = 0.f; }
  #pragma unroll 4
  for (int kk = 0; kk < 128; kk += 4) {
    float2 b0 = *(float2*)&sW1[(kk + 0) * 64 + c0];
    float2 b1 = *(float2*)&sW1[(kk + 1) * 64 + c0];
    float2 b2 = *(float2*)&sW1[(kk + 2) * 64 + c0];
    float2 b3 = *(float2*)&sW1[(kk + 3) * 64 + c0];
    #pragma unroll
    for (int i = 0; i < 8; i++) {
      float4 a = *(float4*)&sH[(r0 + i) * 128 + kk];
      acc[i][0] += a.x * b0.x + a.y * b1.x + a.z * b2.x + a.w * b3.x;
      acc[i][1] += a.x * b0.y + a.y * b1.y + a.z * b2.y + a.w * b3.y;
    }
  }
  float bb0 = ab1[c0], bb1 = ab1[c0 + 1];
  __syncthreads();

  float* a1B = smem;                          // [64][68]
  float* sW2 = smem + 8192;                   // [64][32]
  float* a2B = smem + 8192 + 2048;            // [64][36]
  #pragma unroll
  for (int i = 0; i < 8; i++) {
    float v0 = acc[i][0] + bb0; v0 = fmaxf(v0, 0.2f * v0);
    float v1 = acc[i][1] + bb1; v1 = fmaxf(v1, 0.2f * v1);
    *(float2*)&a1B[(r0 + i) * 68 + c0] = make_float2(v0, v1);
  }
  for (int i4 = tid; i4 < 512; i4 += 256)
    *(float4*)&sW2[i4 * 4] = *(const float4*)(aW2 + i4 * 4);
  __syncthreads();

  int tx2 = tid & 7, ty2 = tid >> 3;
  int cc0 = tx2 * 4, rr0 = ty2 * 2;
  float acc2[2][4];
  #pragma unroll
  for (int i = 0; i < 2; i++)
    #pragma unroll
    for (int j = 0; j < 4; j++) acc2[i][j] = 0.f;
  #pragma unroll 4
  for (int k = 0; k < 64; k += 4) {
    float4 b0 = *(float4*)&sW2[(k + 0) * 32 + cc0];
    float4 b1 = *(float4*)&sW2[(k + 1) * 32 + cc0];
    float4 b2 = *(float4*)&sW2[(k + 2) * 32 + cc0];
    float4 b3 = *(float4*)&sW2[(k + 3) * 32 + cc0];
    #pragma unroll
    for (int i = 0; i < 2; i++) {
      float4 a = *(float4*)&a1B[(rr0 + i) * 68 + k];
      acc2[i][0] += a.x * b0.x + a.y * b1.x + a.z * b2.x + a.w * b3.x;
      acc2[i][1] += a.x * b0.y + a.y * b1.y + a.z * b2.y + a.w * b3.y;
      acc2[i][2] += a.x * b0.z + a.y * b1.z + a.z * b2.z + a.w * b3.z;
      acc2[i][3] += a.x * b0.w + a.y * b1.w + a.z * b2.w + a.w * b3.w;
    }
  }
  float4 bias2 = *(const float4*)(ab2 + cc0);
  #pragma unroll
  for (int i = 0; i < 2; i++) {
    float4 o;
    o.x = acc2[i][0] + bias2.x; o.x = fmaxf(o.x, 0.2f * o.x);
    o.y = acc2[i][1] + bias2.y; o.y = fmaxf(o.y, 0.2f * o.y);
    o.z = acc2[i][2] + bias2.z; o.z = fmaxf(o.z, 0.2f * o.z);
    o.w = acc2[i][3] + bias2.w; o.w = fmaxf(o.w, 0.2f * o.w);
    *(float4*)&a2B[(rr0 + i) * 36 + cc0] = o;
  }
  __syncthreads();

  if (tid < 64) {
    float s = ab3[0];
    #pragma unroll 8
    for (int k = 0; k < 32; k++) s = fmaf(a2B[tid * 36 + k], aW3[k], s);
    s = fminf(fmaxf(s, -10.f), 10.f);
    int node = node0 + tid;
    if (node < n) scores[node] = 1.0f / (1.0f + __expf(-s * temp[0]));
  }
}

// ---------------- attention-weighted pool (batch sorted, h bf16) ----------------
__global__ __launch_bounds__(128) void k_pool(const unsigned short* __restrict__ h,
    const float* __restrict__ scores, const int* __restrict__ batch,
    float* __restrict__ ge, int n) {
  const int NPB = 32;
  int f = threadIdx.x;
  int n0 = blockIdx.x * NPB;
  if (n0 >= n) return;
  int nend = min(n0 + NPB, n);
  float acc = 0.f;
  int cur = batch[n0];
  for (int i = n0; i < nend; i++) {
    int b = batch[i];
    if (b != cur) {
      atomicAdd(&ge[(size_t)cur * D + f], acc);
      acc = 0.f;
      cur = b;
    }
    acc = fmaf(bf2f(h[(size_t)i * D + f]), scores[i], acc);
  }
  atomicAdd(&ge[(size_t)cur * D + f], acc);
}

// ---------------- classifier: block per graph ----------------
__global__ __launch_bounds__(128) void k_classifier(const float* __restrict__ ge,
    const float* __restrict__ cW1, const float* __restrict__ cb1,
    const float* __restrict__ cW2, const float* __restrict__ cb2,
    float* __restrict__ logits, int B) {
  __shared__ float sg[D];
  __shared__ float st[D];
  int g = blockIdx.x;
  int tid = threadIdx.x;
  sg[tid] = ge[(size_t)g * D + tid];
  __syncthreads();
  float a = cb1[tid];
  #pragma unroll 8
  for (int k = 0; k < D; k++) a = fmaf(sg[k], cW1[k * D + tid], a);
  st[tid] = fmaxf(a, 0.f);
  __syncthreads();
  if (tid < 3) {
    float a2 = cb2[tid];
    for (int k = 0; k < D; k++) a2 = fmaf(st[k], cW2[k * 3 + tid], a2);
    logits[(size_t)g * 3 + tid] = a2;
  }
}

extern "C" void kernel_launch(void* const* d_in, const int* in_sizes, int n_in,
                              void* d_out, int out_size, void* d_ws, size_t ws_size,
                              hipStream_t stream) {
  const float* x     = (const float*)d_in[0];
  const int*   ei    = (const int*)d_in[1];
  const int*   batch = (const int*)d_in[2];
  const float* enc_W = (const float*)d_in[3];
  const float* enc_b = (const float*)d_in[4];
  const float* W1    = (const float*)d_in[5];
  const float* b1    = (const float*)d_in[6];
  const float* g1    = (const float*)d_in[7];
  const float* beta1 = (const float*)d_in[8];
  const float* rm1   = (const float*)d_in[9];
  const float* rv1   = (const float*)d_in[10];
  const float* W2    = (const float*)d_in[11];
  const float* b2    = (const float*)d_in[12];
  const float* g2    = (const float*)d_in[13];
  const float* beta2 = (const float*)d_in[14];
  const float* rm2   = (const float*)d_in[15];
  const float* rv2   = (const float*)d_in[16];
  const float* eps   = (const float*)d_in[17];
  const float* og    = (const float*)d_in[18];
  const float* ob    = (const float*)d_in[19];
  const float* orm   = (const float*)d_in[20];
  const float* orv   = (const float*)d_in[21];
  const float* aW1   = (const float*)d_in[22];
  const float* ab1   = (const float*)d_in[23];
  const float* aW2   = (const float*)d_in[24];
  const float* ab2   = (const float*)d_in[25];
  const float* aW3   = (const float*)d_in[26];
  const float* ab3   = (const float*)d_in[27];
  const float* temp  = (const float*)d_in[28];
  const float* cW1   = (const float*)d_in[29];
  const float* cb1   = (const float*)d_in[30];
  const float* cW2   = (const float*)d_in[31];
  const float* cb2   = (const float*)d_in[32];

  int N = in_sizes[0] / D;
  int E = in_sizes[1] / 2;
  int B = (out_size - N) / (3 + D);
  int nb = (N + 511) >> BSH;     // buckets of 512 nodes (<=128 for N<=65536)

  // workspace layout (hbufA/hbufB ping-pong across layers)
  unsigned short* hbufA = (unsigned short*)d_ws;
  unsigned short* hbufB = hbufA + (size_t)N * D;
  int* row_ptr = (int*)(hbufB + (size_t)N * D);
  int* colidx  = row_ptr + N + 1;
  int* bcnt    = colidx + E;            // nb*BPAD
  int* boff    = bcnt + nb * BPAD;      // nb+1
  int* bcur    = boff + nb + 1;         // nb*BPAD
  uintptr_t p = (uintptr_t)(bcur + nb * BPAD);
  p = (p + 15) & ~(uintptr_t)15;
  unsigned* pairs = (unsigned*)p;       // E packed records
  unsigned short* WT = (unsigned short*)(pairs + E);   // 7*128*128 bf16
  float4* sc_all = (float4*)(WT + 7 * D * D);          // 7*128 float4

  float* logits = (float*)d_out;
  float* ge     = logits + (size_t)B * 3;
  float* scores = ge + (size_t)B * D;

  k_prep_w<<<112, 256, 0, stream>>>(enc_W, W1, W2, WT);
  k_scales<<<7, 128, 0, stream>>>(enc_b, b1, g1, beta1, rm1, rv1,
                                  b2, g2, beta2, rm2, rv2, og, ob, orm, orv, sc_all);

  // bucketed CSR build (packed 4B records, LDS-staged scatter)
  hipMemsetAsync(bcnt, 0, (size_t)nb * BPAD * sizeof(int), stream);
  k_bhist<<<256, 256, 0, stream>>>(ei, bcnt, E, nb);
  k_bktscan<<<1, 128, 0, stream>>>(bcnt, boff, bcur, row_ptr, nb, N, E);
  k_bscatter<<<(E + 2047) / 2048, 256, 0, stream>>>(ei, bcur, pairs, E, nb);
  k_bplace<<<nb, 256, 0, stream>>>(pairs, boff, row_ptr, colidx, N);

  int gblocks = (N + 63) / 64;
  int lblocks = (N + 31) / 32;
  // encoder: h = relu(x@enc_W + enc_b)
  k_mfma<<<gblocks, 256, 0, stream>>>(x, WT, sc_all, hbufA, N);

  unsigned short* cur = hbufA;
  unsigned short* nxt = hbufB;
  for (int l = 0; l < 3; l++) {
    k_layer<<<lblocks, 128, 0, stream>>>(cur, row_ptr, colidx, eps, l,
        WT + (size_t)(1 + 2 * l) * D * D, WT + (size_t)(2 + 2 * l) * D * D,
        sc_all + (1 + 2 * l) * D, sc_all + (2 + 2 * l) * D, nxt, N);
    unsigned short* t = cur; cur = nxt; nxt = t;
  }

  k_attention<<<gblocks, 256, 0, stream>>>(cur, aW1, ab1, aW2, ab2, aW3, ab3,
                                           temp, scores, N);
  hipMemsetAsync(ge, 0, (size_t)B * D * sizeof(float), stream);
  k_pool<<<(N + 31) / 32, 128, 0, stream>>>(cur, scores, batch, ge, N);
  k_classifier<<<B, 128, 0, stream>>>(ge, cW1, cb1, cW2, cb2, logits, B);
}

// Round 15
// 435.861 us; speedup vs baseline: 1.0956x; 1.0105x over previous
//
#include <hip/hip_runtime.h>
#include <math.h>

#define D 128
#define BSH 9                    // bucket = dst >> 9 (512 nodes/bucket)
#define NBMAX 128                // max buckets (N <= 65536)
#define SCAP 64                  // per-bucket LDS staging capacity
#define BPAD 16                  // bucket cursors padded to 64B lines
#define SLSH 13                  // src slice = src >> 13 (8 slices for N<=65536)

typedef short bf16x8 __attribute__((ext_vector_type(8)));
typedef float f32x4 __attribute__((ext_vector_type(4)));

__device__ inline unsigned short f2bf(float f) {  // RNE fp32->bf16
  unsigned u = __float_as_uint(f);
  return (unsigned short)((u + 0x7fffu + ((u >> 16) & 1u)) >> 16);
}
__device__ inline float bf2f(unsigned short b) {
  return __uint_as_float(((unsigned)b) << 16);
}
__device__ inline void acc_u4(float* a, uint4 v) {
  a[0] += __uint_as_float(v.x << 16);
  a[1] += __uint_as_float(v.x & 0xffff0000u);
  a[2] += __uint_as_float(v.y << 16);
  a[3] += __uint_as_float(v.y & 0xffff0000u);
  a[4] += __uint_as_float(v.z << 16);
  a[5] += __uint_as_float(v.z & 0xffff0000u);
  a[6] += __uint_as_float(v.w << 16);
  a[7] += __uint_as_float(v.w & 0xffff0000u);
}

// ---------------- bucketed CSR build (records packed: src<<16 | dst) ----------------
__global__ __launch_bounds__(256) void k_bhist(const int* __restrict__ ei,
    int* __restrict__ bcnt, int E, int nb) {
  __shared__ int h[NBMAX];
  for (int i = threadIdx.x; i < NBMAX; i += 256) h[i] = 0;
  __syncthreads();
  for (int e = blockIdx.x * 256 + threadIdx.x; e < E; e += gridDim.x * 256)
    atomicAdd(&h[ei[E + e] >> BSH], 1);
  __syncthreads();
  for (int i = threadIdx.x; i < nb; i += 256)
    if (h[i]) atomicAdd(&bcnt[i * BPAD], h[i]);
}

__global__ __launch_bounds__(128) void k_bktscan(const int* __restrict__ bcnt,
    int* __restrict__ boff, int* __restrict__ bcur, int* __restrict__ row_ptr,
    int nb, int N, int E) {
  int tid = threadIdx.x;
  int v = (tid < nb) ? bcnt[tid * BPAD] : 0;
  int lane = tid & 63, w = tid >> 6;
  int incl = v;
  #pragma unroll
  for (int off = 1; off < 64; off <<= 1) {
    int t = __shfl_up(incl, off, 64);
    if (lane >= off) incl += t;
  }
  __shared__ int ws[2];
  if (lane == 63) ws[w] = incl;
  __syncthreads();
  int excl = incl - v + (w ? ws[0] : 0);
  if (tid < nb) { boff[tid] = excl; bcur[tid * BPAD] = excl; }
  if (tid == nb - 1) boff[nb] = excl + v;
  if (tid == 0) row_ptr[N] = E;
}

__global__ __launch_bounds__(256) void k_bscatter(const int* __restrict__ ei,
    int* __restrict__ bcur, unsigned* __restrict__ pairs, int E, int nb) {
  __shared__ unsigned stage[NBMAX * SCAP];   // 32KB
  __shared__ int scnt[NBMAX];
  __shared__ int sbase[NBMAX];
  __shared__ int pref[NBMAX + 1];
  int tid = threadIdx.x;
  int c0 = blockIdx.x * 2048;
  if (c0 >= E) return;
  int cend = min(c0 + 2048, E);
  for (int i = tid; i < NBMAX; i += 256) scnt[i] = 0;
  __syncthreads();
  for (int e = c0 + tid; e < cend; e += 256) {
    int src = ei[e], dst = ei[E + e];
    unsigned rec = ((unsigned)src << 16) | (unsigned)dst;   // N <= 65536
    int b = dst >> BSH;
    int pos = atomicAdd(&scnt[b], 1);
    if (pos < SCAP) stage[b * SCAP + pos] = rec;
    else {
      int gp = atomicAdd(&bcur[b * BPAD], 1);
      pairs[gp] = rec;
    }
  }
  __syncthreads();
  for (int b = tid; b < nb; b += 256) {
    int cnt = min(scnt[b], SCAP);
    sbase[b] = cnt ? atomicAdd(&bcur[b * BPAD], cnt) : 0;
  }
  __syncthreads();
  if (tid == 0) {
    int r = 0;
    for (int b = 0; b < nb; b++) { pref[b] = r; r += min(scnt[b], SCAP); }
    pref[nb] = r;
  }
  __syncthreads();
  int T = pref[nb];
  for (int j = tid; j < T; j += 256) {
    int lo = 0, hi = nb;
    while (hi - lo > 1) { int mid = (lo + hi) >> 1; if (pref[mid] <= j) lo = mid; else hi = mid; }
    int i = j - pref[lo];
    pairs[sbase[lo] + i] = stage[lo * SCAP + i];
  }
}

// per-bucket two-key counting sort: key = (dst_local<<3)|src_slice -> row_ptr + col
// src-slice-minor order gives temporal L2 locality in the gather (slice = 1.6MB).
__global__ __launch_bounds__(256) void k_bplace(const unsigned* __restrict__ pairs,
    const int* __restrict__ boff, int* __restrict__ row_ptr,
    int* __restrict__ col, int N) {
  int b = blockIdx.x, tid = threadIdx.x;
  int n0 = b << BSH;
  int nn = min(512, N - n0);
  int beg = boff[b], end = boff[b + 1];
  int cnt = end - beg;
  __shared__ int hist[4096];     // 16KB; reused as cursor after scan
  __shared__ int wt[4];
  for (int i = tid; i < 4096; i += 256) hist[i] = 0;
  __syncthreads();
  for (int i = tid; i < cnt; i += 256) {
    unsigned u = pairs[beg + i];
    int key = (((int)u & 511) << 3) | (int)((u >> 16) >> SLSH);
    atomicAdd(&hist[key], 1);
  }
  __syncthreads();
  // scan 4096 bins: thread owns 16 consecutive bins
  int base16 = tid * 16;
  int loc[16];
  int s = 0;
  #pragma unroll
  for (int j = 0; j < 16; j++) { loc[j] = hist[base16 + j]; s += loc[j]; }
  int lane = tid & 63, w = tid >> 6;
  int incl = s;
  #pragma unroll
  for (int off = 1; off < 64; off <<= 1) {
    int t = __shfl_up(incl, off, 64);
    if (lane >= off) incl += t;
  }
  if (lane == 63) wt[w] = incl;
  __syncthreads();
  if (tid == 0) {
    int r = 0;
    #pragma unroll
    for (int i = 0; i < 4; i++) { int t = wt[i]; wt[i] = r; r += t; }
  }
  __syncthreads();
  int run = wt[w] + incl - s;    // exclusive prefix for this thread's first bin
  #pragma unroll
  for (int j = 0; j < 16; j++) {
    int bin = base16 + j;
    hist[bin] = run;             // becomes cursor
    if ((bin & 7) == 0) {
      int nl = bin >> 3;
      if (nl < nn) row_ptr[n0 + nl] = beg + run;
    }
    run += loc[j];
  }
  __syncthreads();
  for (int i = tid; i < cnt; i += 256) {
    unsigned u = pairs[beg + i];
    int src = (int)(u >> 16);
    int key = (((int)u & 511) << 3) | (src >> SLSH);
    int p = atomicAdd(&hist[key], 1);
    col[beg + p] = src;
  }
}

// ---------------- weight prep: WT[n][k] = bf16(W[k][n]), 112 blocks ----------------
__global__ __launch_bounds__(256) void k_prep_w(const float* __restrict__ encW,
    const float* __restrict__ W1, const float* __restrict__ W2,
    unsigned short* __restrict__ WT) {
  int b = blockIdx.x >> 4;        // matrix id 0..6
  int chunk = blockIdx.x & 15;    // 1024 elems per chunk
  const float* src;
  if (b == 0) src = encW;
  else if (b & 1) src = W1 + (size_t)((b - 1) / 2) * D * D;
  else src = W2 + (size_t)(b / 2 - 1) * D * D;
  unsigned short* dst = WT + (size_t)b * D * D;
  int e = chunk * 1024 + threadIdx.x;
  #pragma unroll
  for (int it = 0; it < 4; it++, e += 256) {
    int n = e >> 7, k = e & 127;
    dst[n * D + k] = f2bf(src[k * D + n]);
  }
}

// ---------------- fused epilogue scales ----------------
__global__ __launch_bounds__(128) void k_scales(
    const float* __restrict__ enc_b,
    const float* __restrict__ b1, const float* __restrict__ g1,
    const float* __restrict__ be1, const float* __restrict__ rm1, const float* __restrict__ rv1,
    const float* __restrict__ b2, const float* __restrict__ g2,
    const float* __restrict__ be2, const float* __restrict__ rm2, const float* __restrict__ rv2,
    const float* __restrict__ og, const float* __restrict__ ob,
    const float* __restrict__ orm, const float* __restrict__ orv,
    float4* __restrict__ scales) {
  int g = blockIdx.x, c = threadIdx.x;
  float s1 = 1.f, t1 = 0.f, s2 = 1.f, t2 = 0.f;
  if (g == 0) {
    t1 = enc_b[c];
  } else if (g & 1) {
    int l = (g - 1) / 2, i = l * D + c;
    float inv = rsqrtf(rv1[i] + 1e-5f);
    s1 = g1[i] * inv;
    t1 = (b1[i] - rm1[i]) * s1 + be1[i];
  } else {
    int l = g / 2 - 1, i = l * D + c;
    float inv = rsqrtf(rv2[i] + 1e-5f);
    s1 = g2[i] * inv;
    t1 = (b2[i] - rm2[i]) * s1 + be2[i];
    float inv2 = rsqrtf(orv[i] + 1e-5f);
    s2 = og[i] * inv2;
    t2 = ob[i] - orm[i] * s2;
  }
  scales[g * D + c] = make_float4(s1, t1, s2, t2);
}

#define TSTRIDE 136

// shared device helpers for the MFMA kernels
__device__ inline void mfma_gemm(const bf16x8* afr,
    const unsigned short* __restrict__ WT, int l16, int quad, f32x4* acc) {
  #pragma unroll
  for (int t = 0; t < 8; t++) acc[t] = (f32x4){0.f, 0.f, 0.f, 0.f};
  #pragma unroll
  for (int kk = 0; kk < 4; kk++) {
    int koff = kk * 32 + quad * 8;
    #pragma unroll
    for (int t = 0; t < 8; t++) {
      bf16x8 bfr = *(const bf16x8*)(WT + (size_t)(16 * t + l16) * D + koff);
      acc[t] = __builtin_amdgcn_mfma_f32_16x16x32_bf16(afr[kk], bfr, acc[t], 0, 0, 0);
    }
  }
}

__device__ inline void epilogue_to_lds(const f32x4* acc,
    const float4* __restrict__ scales, unsigned short* stile,
    int rl, int l16) {
  #pragma unroll
  for (int t = 0; t < 8; t++) {
    int colc = 16 * t + l16;
    float4 sc = scales[colc];
    #pragma unroll
    for (int reg = 0; reg < 4; reg++) {
      float y = acc[t][reg] * sc.x + sc.y;
      y = fmaxf(y, 0.f);
      y = y * sc.z + sc.w;
      y = fmaxf(y, 0.f);
      stile[(rl + reg) * TSTRIDE + colc] = f2bf(y);
    }
  }
}

// ---------------- encoder MFMA GEMM (fp32 in) ----------------
__global__ __launch_bounds__(256) void k_mfma(const float* __restrict__ in,
    const unsigned short* __restrict__ WT, const float4* __restrict__ scales,
    unsigned short* __restrict__ out, int N) {
  __shared__ unsigned short stile[64 * TSTRIDE];
  int tid = threadIdx.x;
  int wave = tid >> 6, lane = tid & 63;
  int quad = lane >> 4, l16 = lane & 15;
  int rc = min(blockIdx.x * 64 + wave * 16 + l16, N - 1);
  const float* arow = in + (size_t)rc * D;
  bf16x8 afr[4];
  #pragma unroll
  for (int kk = 0; kk < 4; kk++) {
    int koff = kk * 32 + quad * 8;
    float4 lo = *(const float4*)(arow + koff);
    float4 hi = *(const float4*)(arow + koff + 4);
    afr[kk][0] = f2bf(lo.x); afr[kk][1] = f2bf(lo.y);
    afr[kk][2] = f2bf(lo.z); afr[kk][3] = f2bf(lo.w);
    afr[kk][4] = f2bf(hi.x); afr[kk][5] = f2bf(hi.y);
    afr[kk][6] = f2bf(hi.z); afr[kk][7] = f2bf(hi.w);
  }
  f32x4 acc[8];
  mfma_gemm(afr, WT, l16, quad, acc);
  epilogue_to_lds(acc, scales, stile, wave * 16 + quad * 4, l16);
  __syncthreads();
  #pragma unroll
  for (int u = tid; u < 1024; u += 256) {
    int r = u >> 4, cs = (u & 15) * 8;
    int row = blockIdx.x * 64 + r;
    if (row < N)
      *(uint4*)(out + (size_t)row * D + cs) = *(const uint4*)&stile[r * TSTRIDE + cs];
  }
}

// ---------------- fused GIN layer: 128 threads / 32-row tile ----------------
__global__ __launch_bounds__(128) void k_layer(const unsigned short* __restrict__ h,
    const int* __restrict__ row_ptr, const int* __restrict__ col,
    const float* __restrict__ eps, int layer,
    const unsigned short* __restrict__ WT1, const unsigned short* __restrict__ WT2,
    const float4* __restrict__ sc1, const float4* __restrict__ sc2,
    unsigned short* __restrict__ out, int N) {
  __shared__ unsigned short stile[32 * TSTRIDE];   // 8.7KB
  int tid = threadIdx.x;
  float ep = 1.0f + eps[layer];
  int rloc = tid >> 4;           // 0..7: 16 lanes per node
  int c = (tid & 15) << 3;       // 8 bf16 cols per lane (16B loads)

  // phase A: aggregate 32 nodes (4 sub-batches of 8) -> stile (bf16 m-tile)
  for (int sub = 0; sub < 4; sub++) {
    int nl = sub * 8 + rloc;
    int node = blockIdx.x * 32 + nl;
    float acc[8];
    #pragma unroll
    for (int j = 0; j < 8; j++) acc[j] = 0.f;
    if (node < N) {
      int beg = row_ptr[node], end = row_ptr[node + 1];
      int i = beg;
      for (; i + 3 < end; i += 4) {
        int s0 = col[i], s1 = col[i + 1], s2 = col[i + 2], s3 = col[i + 3];
        uint4 v0 = *(const uint4*)(h + (size_t)s0 * D + c);
        uint4 v1 = *(const uint4*)(h + (size_t)s1 * D + c);
        uint4 v2 = *(const uint4*)(h + (size_t)s2 * D + c);
        uint4 v3 = *(const uint4*)(h + (size_t)s3 * D + c);
        acc_u4(acc, v0); acc_u4(acc, v1); acc_u4(acc, v2); acc_u4(acc, v3);
      }
      for (; i < end; i++)
        acc_u4(acc, *(const uint4*)(h + (size_t)col[i] * D + c));
      uint4 hv = *(const uint4*)(h + (size_t)node * D + c);
      float sv[8] = {0.f, 0.f, 0.f, 0.f, 0.f, 0.f, 0.f, 0.f};
      acc_u4(sv, hv);
      #pragma unroll
      for (int j = 0; j < 8; j++) acc[j] = fmaf(ep, sv[j], acc[j]);
    }
    uint4 o;
    o.x = (unsigned)f2bf(acc[0]) | ((unsigned)f2bf(acc[1]) << 16);
    o.y = (unsigned)f2bf(acc[2]) | ((unsigned)f2bf(acc[3]) << 16);
    o.z = (unsigned)f2bf(acc[4]) | ((unsigned)f2bf(acc[5]) << 16);
    o.w = (unsigned)f2bf(acc[6]) | ((unsigned)f2bf(acc[7]) << 16);
    *(uint4*)&stile[nl * TSTRIDE + c] = o;
  }
  __syncthreads();

  // phase B: GEMM pair (2 waves x 16 rows), A-fragments from stile
  int wave = tid >> 6, lane = tid & 63;
  int quad = lane >> 4, l16 = lane & 15;
  int rl = wave * 16 + quad * 4;
  bf16x8 afr[4];
  const unsigned short* lrow = &stile[(wave * 16 + l16) * TSTRIDE];
  #pragma unroll
  for (int kk = 0; kk < 4; kk++)
    afr[kk] = *(const bf16x8*)(lrow + kk * 32 + quad * 8);
  __syncthreads();   // all reads done before epilogue overwrites

  f32x4 acc[8];
  mfma_gemm(afr, WT1, l16, quad, acc);
  epilogue_to_lds(acc, sc1, stile, rl, l16);
  __syncthreads();

  #pragma unroll
  for (int kk = 0; kk < 4; kk++)
    afr[kk] = *(const bf16x8*)(lrow + kk * 32 + quad * 8);
  __syncthreads();

  mfma_gemm(afr, WT2, l16, quad, acc);
  epilogue_to_lds(acc, sc2, stile, rl, l16);
  __syncthreads();

  // writeout: 32 rows x 128 shorts = 512 uint4s; 4 per thread
  #pragma unroll
  for (int u = tid; u < 512; u += 128) {
    int r = u >> 4, cs = (u & 15) * 8;
    int row = blockIdx.x * 32 + r;
    if (row < N)
      *(uint4*)(out + (size_t)row * D + cs) = *(const uint4*)&stile[r * TSTRIDE + cs];
  }
}

// ---------------- attention MLP: fused LDS-tiled 3-stage GEMM (h bf16) ----------------
__global__ __launch_bounds__(256) void k_attention(const unsigned short* __restrict__ h,
    const float* __restrict__ aW1, const float* __restrict__ ab1,
    const float* __restrict__ aW2, const float* __restrict__ ab2,
    const float* __restrict__ aW3, const float* __restrict__ ab3,
    const float* __restrict__ temp, float* __restrict__ scores, int n) {
  __shared__ float smem[16384];              // 64KB
  float* sH  = smem;                         // [64][128]
  float* sW1 = smem + 8192;                  // [128][64]
  int tid = threadIdx.x;
  int node0 = blockIdx.x * 64;

  for (int i = tid; i < 1024; i += 256) {
    int r = i >> 4, c8 = (i & 15) << 3;
    int nd = min(node0 + r, n - 1);
    uint4 u = *(const uint4*)(h + (size_t)nd * D + c8);
    float* dst = &sH[r * 128 + c8];
    dst[0] = __uint_as_float(u.x << 16); dst[1] = __uint_as_float(u.x & 0xffff0000u);
    dst[2] = __uint_as_float(u.y << 16); dst[3] = __uint_as_float(u.y & 0xffff0000u);
    dst[4] = __uint_as_float(u.z << 16); dst[5] = __uint_as_float(u.z & 0xffff0000u);
    dst[6] = __uint_as_float(u.w << 16); dst[7] = __uint_as_float(u.w & 0xffff0000u);
  }
  for (int i4 = tid; i4 < 2048; i4 += 256)
    *(float4*)&sW1[i4 * 4] = *(const float4*)(aW1 + i4 * 4);
  __syncthreads();

  int tx = tid & 31, ty = tid >> 5;
  int c0 = tx * 2, r0 = ty * 8;
  float acc[8][2];
  #pragma unroll
  for (int i = 0; i < 8; i++) { acc[i][0] = 0.f; acc[i][1] = 0.f; }
  #pragma unroll 4
  for (int kk = 0; kk < 128; kk += 4) {
    float2 b0 = *(float2*)&sW1[(kk + 0) * 64 + c0];
    float2 b1 = *(float2*)&sW1[(kk + 1) * 64 + c0];
    float2 b2 = *(float2*)&sW1[(kk + 2) * 64 + c0];
    float2 b3 = *(float2*)&sW1[(kk + 3) * 64 + c0];
    #pragma unroll
    for (int i = 0; i < 8; i++) {
      float4 a = *(float4*)&sH[(r0 + i) * 128 + kk];
      acc[i][0] += a.x * b0.x + a.y * b1.x + a.z * b2.x + a.w * b3.x;
      acc[i][1] += a.x * b0.y + a.y * b1.y + a.z * b2.y + a.w * b3.y;
    }
  }
  float bb0 = ab1[c0], bb1 = ab1[c0 + 1];
  __syncthreads();

  float* a1B = smem;                          // [64][68]
  float* sW2 = smem + 8192;                   // [64][32]
  float* a2B = smem + 8192 + 2048;            // [64][36]
  #pragma unroll
  for (int i = 0; i < 8; i++) {
    float v0 = acc[i][0] + bb0; v0 = fmaxf(v0, 0.2f * v0);
    float v1 = acc[i][1] + bb1; v1 = fmaxf(v1, 0.2f * v1);
    *(float2*)&a1B[(r0 + i) * 68 + c0] = make_float2(v0, v1);
  }
  for (int i4 = tid; i4 < 512; i4 += 256)
    *(float4*)&sW2[i4 * 4] = *(const float4*)(aW2 + i4 * 4);
  __syncthreads();

  int tx2 = tid & 7, ty2 = tid >> 3;
  int cc0 = tx2 * 4, rr0 = ty2 * 2;
  float acc2[2][4];
  #pragma unroll
  for (int i = 0; i < 2; i++)
    #pragma unroll
    for (int j = 0; j < 4; j++) acc2[i][j] = 0.f;
  #pragma unroll 4
  for (int k = 0; k < 64; k += 4) {
    float4 b0 = *(float4*)&sW2[(k + 0) * 32 + cc0];
    float4 b1 = *(float4*)&sW2[(k + 1) * 32 + cc0];
    float4 b2 = *(float4*)&sW2[(k + 2) * 32 + cc0];
    float4 b3 = *(float4*)&sW2[(k + 3) * 32 + cc0];
    #pragma unroll
    for (int i = 0; i < 2; i++) {
      float4 a = *(float4*)&a1B[(rr0 + i) * 68 + k];
      acc2[i][0] += a.x * b0.x + a.y * b1.x + a.z * b2.x + a.w * b3.x;
      acc2[i][1] += a.x * b0.y + a.y * b1.y + a.z * b2.y + a.w * b3.y;
      acc2[i][2] += a.x * b0.z + a.y * b1.z + a.z * b2.z + a.w * b3.z;
      acc2[i][3] += a.x * b0.w + a.y * b1.w + a.z * b2.w + a.w * b3.w;
    }
  }
  float4 bias2 = *(const float4*)(ab2 + cc0);
  #pragma unroll
  for (int i = 0; i < 2; i++) {
    float4 o;
    o.x = acc2[i][0] + bias2.x; o.x = fmaxf(o.x, 0.2f * o.x);
    o.y = acc2[i][1] + bias2.y; o.y = fmaxf(o.y, 0.2f * o.y);
    o.z = acc2[i][2] + bias2.z; o.z = fmaxf(o.z, 0.2f * o.z);
    o.w = acc2[i][3] + bias2.w; o.w = fmaxf(o.w, 0.2f * o.w);
    *(float4*)&a2B[(rr0 + i) * 36 + cc0] = o;
  }
  __syncthreads();

  if (tid < 64) {
    float s = ab3[0];
    #pragma unroll 8
    for (int k = 0; k < 32; k++) s = fmaf(a2B[tid * 36 + k], aW3[k], s);
    s = fminf(fmaxf(s, -10.f), 10.f);
    int node = node0 + tid;
    if (node < n) scores[node] = 1.0f / (1.0f + __expf(-s * temp[0]));
  }
}

// ---------------- attention-weighted pool (batch sorted, h bf16) ----------------
__global__ __launch_bounds__(128) void k_pool(const unsigned short* __restrict__ h,
    const float* __restrict__ scores, const int* __restrict__ batch,
    float* __restrict__ ge, int n) {
  const int NPB = 32;
  int f = threadIdx.x;
  int n0 = blockIdx.x * NPB;
  if (n0 >= n) return;
  int nend = min(n0 + NPB, n);
  float acc = 0.f;
  int cur = batch[n0];
  for (int i = n0; i < nend; i++) {
    int b = batch[i];
    if (b != cur) {
      atomicAdd(&ge[(size_t)cur * D + f], acc);
      acc = 0.f;
      cur = b;
    }
    acc = fmaf(bf2f(h[(size_t)i * D + f]), scores[i], acc);
  }
  atomicAdd(&ge[(size_t)cur * D + f], acc);
}

// ---------------- classifier: block per graph ----------------
__global__ __launch_bounds__(128) void k_classifier(const float* __restrict__ ge,
    const float* __restrict__ cW1, const float* __restrict__ cb1,
    const float* __restrict__ cW2, const float* __restrict__ cb2,
    float* __restrict__ logits, int B) {
  __shared__ float sg[D];
  __shared__ float st[D];
  int g = blockIdx.x;
  int tid = threadIdx.x;
  sg[tid] = ge[(size_t)g * D + tid];
  __syncthreads();
  float a = cb1[tid];
  #pragma unroll 8
  for (int k = 0; k < D; k++) a = fmaf(sg[k], cW1[k * D + tid], a);
  st[tid] = fmaxf(a, 0.f);
  __syncthreads();
  if (tid < 3) {
    float a2 = cb2[tid];
    for (int k = 0; k < D; k++) a2 = fmaf(st[k], cW2[k * 3 + tid], a2);
    logits[(size_t)g * 3 + tid] = a2;
  }
}

extern "C" void kernel_launch(void* const* d_in, const int* in_sizes, int n_in,
                              void* d_out, int out_size, void* d_ws, size_t ws_size,
                              hipStream_t stream) {
  const float* x     = (const float*)d_in[0];
  const int*   ei    = (const int*)d_in[1];
  const int*   batch = (const int*)d_in[2];
  const float* enc_W = (const float*)d_in[3];
  const float* enc_b = (const float*)d_in[4];
  const float* W1    = (const float*)d_in[5];
  const float* b1    = (const float*)d_in[6];
  const float* g1    = (const float*)d_in[7];
  const float* beta1 = (const float*)d_in[8];
  const float* rm1   = (const float*)d_in[9];
  const float* rv1   = (const float*)d_in[10];
  const float* W2    = (const float*)d_in[11];
  const float* b2    = (const float*)d_in[12];
  const float* g2    = (const float*)d_in[13];
  const float* beta2 = (const float*)d_in[14];
  const float* rm2   = (const float*)d_in[15];
  const float* rv2   = (const float*)d_in[16];
  const float* eps   = (const float*)d_in[17];
  const float* og    = (const float*)d_in[18];
  const float* ob    = (const float*)d_in[19];
  const float* orm   = (const float*)d_in[20];
  const float* orv   = (const float*)d_in[21];
  const float* aW1   = (const float*)d_in[22];
  const float* ab1   = (const float*)d_in[23];
  const float* aW2   = (const float*)d_in[24];
  const float* ab2   = (const float*)d_in[25];
  const float* aW3   = (const float*)d_in[26];
  const float* ab3   = (const float*)d_in[27];
  const float* temp  = (const float*)d_in[28];
  const float* cW1   = (const float*)d_in[29];
  const float* cb1   = (const float*)d_in[30];
  const float* cW2   = (const float*)d_in[31];
  const float* cb2   = (const float*)d_in[32];

  int N = in_sizes[0] / D;
  int E = in_sizes[1] / 2;
  int B = (out_size - N) / (3 + D);
  int nb = (N + 511) >> BSH;     // buckets of 512 nodes (<=128 for N<=65536)

  // workspace layout (hbufA/hbufB ping-pong across layers)
  unsigned short* hbufA = (unsigned short*)d_ws;
  unsigned short* hbufB = hbufA + (size_t)N * D;
  int* row_ptr = (int*)(hbufB + (size_t)N * D);
  int* colidx  = row_ptr + N + 1;
  int* bcnt    = colidx + E;            // nb*BPAD
  int* boff    = bcnt + nb * BPAD;      // nb+1
  int* bcur    = boff + nb + 1;         // nb*BPAD
  uintptr_t p = (uintptr_t)(bcur + nb * BPAD);
  p = (p + 15) & ~(uintptr_t)15;
  unsigned* pairs = (unsigned*)p;       // E packed records
  unsigned short* WT = (unsigned short*)(pairs + E);   // 7*128*128 bf16
  float4* sc_all = (float4*)(WT + 7 * D * D);          // 7*128 float4

  float* logits = (float*)d_out;
  float* ge     = logits + (size_t)B * 3;
  float* scores = ge + (size_t)B * D;

  k_prep_w<<<112, 256, 0, stream>>>(enc_W, W1, W2, WT);
  k_scales<<<7, 128, 0, stream>>>(enc_b, b1, g1, beta1, rm1, rv1,
                                  b2, g2, beta2, rm2, rv2, og, ob, orm, orv, sc_all);

  // bucketed CSR build (packed 4B records, LDS-staged scatter, (dst,src-slice) sort)
  hipMemsetAsync(bcnt, 0, (size_t)nb * BPAD * sizeof(int), stream);
  k_bhist<<<256, 256, 0, stream>>>(ei, bcnt, E, nb);
  k_bktscan<<<1, 128, 0, stream>>>(bcnt, boff, bcur, row_ptr, nb, N, E);
  k_bscatter<<<(E + 2047) / 2048, 256, 0, stream>>>(ei, bcur, pairs, E, nb);
  k_bplace<<<nb, 256, 0, stream>>>(pairs, boff, row_ptr, colidx, N);

  int gblocks = (N + 63) / 64;
  int lblocks = (N + 31) / 32;
  // encoder: h = relu(x@enc_W + enc_b)
  k_mfma<<<gblocks, 256, 0, stream>>>(x, WT, sc_all, hbufA, N);

  unsigned short* cur = hbufA;
  unsigned short* nxt = hbufB;
  for (int l = 0; l < 3; l++) {
    k_layer<<<lblocks, 128, 0, stream>>>(cur, row_ptr, colidx, eps, l,
        WT + (size_t)(1 + 2 * l) * D * D, WT + (size_t)(2 + 2 * l) * D * D,
        sc_all + (1 + 2 * l) * D, sc_all + (2 + 2 * l) * D, nxt, N);
    unsigned short* t = cur; cur = nxt; nxt = t;
  }

  k_attention<<<gblocks, 256, 0, stream>>>(cur, aW1, ab1, aW2, ab2, aW3, ab3,
                                           temp, scores, N);
  hipMemsetAsync(ge, 0, (size_t)B * D * sizeof(float), stream);
  k_pool<<<(N + 31) / 32, 128, 0, stream>>>(cur, scores, batch, ge, N);
  k_classifier<<<B, 128, 0, stream>>>(ge, cW1, cb1, cW2, cb2, logits, B);
}